// Round 6
// baseline (563.446 us; speedup 1.0000x reference)
//
#include <hip/hip_runtime.h>
#include <stdint.h>

// ---------------------------------------------------------------------------
// HeteroGraphSAGE encoder, MI355X round 6.
// Round-5 post-mortem: gemm_update latency-bound at 1.6 TB/s (4 serial HBM
// round-trips per wave from `#pragma unroll 1` on the K-chunk loop + 4
// waves/SIMD). Fix: prefetch the FULL K of X fragments per wave into
// registers (8 x bf16x8 = 128B/lane in flight), then run all 64 MFMAs.
// Also merged cvt3+prep_weights into one prep_all launch.
// CSR build / agg4 / buffers unchanged from round 5.
// ---------------------------------------------------------------------------

#define NUSR 200000
#define NMOV 50000
#define NTAG 20000
#define FDIM 64
#define HDIM 128
#define NE1  800000
#define NE2  400000

#define OFF_RM 0
#define OFF_RU (NMOV)
#define OFF_TM (NMOV + NUSR)
#define OFF_TT (NMOV + NUSR + NMOV)
#define NTOT   (2 * NMOV + NUSR + NTAG)      // 320000
#define ETOT   (2 * NE1 + 2 * NE2)           // 2.4M
#define WHH    (HDIM * HDIM)

// bucket layout (round 4): mean ~4096 edges/bucket
#define NB0 196
#define NB1 196
#define NB2 98
#define NB3 157
#define NB  (NB0 + NB1 + NB2 + NB3)          // 647
#define S1_EPB 8192
#define S1_B0 98
#define S1_B1 98
#define S1_B2 49
#define S1_B3 49
#define S1_NBLK (S1_B0 + S1_B1 + S1_B2 + S1_B3)  // 294
#define CAP 6144

typedef short bf16x8 __attribute__((ext_vector_type(8)));
typedef float f32x4 __attribute__((ext_vector_type(4)));

static inline int cdiv(int a, int b) { return (a + b - 1) / b; }

__device__ __forceinline__ float bf2f(unsigned short u) {
    union { unsigned int i; float f; } c;
    c.i = ((unsigned int)u) << 16;
    return c.f;
}
__device__ __forceinline__ unsigned short f2bf(float f) {
    union { float f; unsigned int i; } c;
    c.f = f;
    unsigned int i = c.i;
    return (unsigned short)((i + 0x7fffu + ((i >> 16) & 1u)) >> 16);  // RNE
}

// ---------------------------------------------------------------------------
// CSR build (round-4 bucketized design, unchanged)
// ---------------------------------------------------------------------------
struct SegInfo {
    int e0, eN, sh, sbb, nb;
    const int* dstA;
    const int* srcA;
};
__device__ __forceinline__ SegInfo seg_decode(int blk, const int* ru, const int* rm,
                                              const int* tm, const int* tt) {
    SegInfo s;
    if (blk < S1_B0) {
        s.e0 = blk * S1_EPB; s.eN = NE1; s.sh = 8;  s.sbb = 0;                 s.nb = NB0;
        s.dstA = rm; s.srcA = ru;
    } else if (blk < S1_B0 + S1_B1) {
        s.e0 = (blk - S1_B0) * S1_EPB; s.eN = NE1; s.sh = 10; s.sbb = NB0;     s.nb = NB1;
        s.dstA = ru; s.srcA = rm;
    } else if (blk < S1_B0 + S1_B1 + S1_B2) {
        s.e0 = (blk - S1_B0 - S1_B1) * S1_EPB; s.eN = NE2; s.sh = 9;
        s.sbb = NB0 + NB1; s.nb = NB2;
        s.dstA = tm; s.srcA = tt;
    } else {
        s.e0 = (blk - S1_B0 - S1_B1 - S1_B2) * S1_EPB; s.eN = NE2; s.sh = 7;
        s.sbb = NB0 + NB1 + NB2; s.nb = NB3;
        s.dstA = tt; s.srcA = tm;
    }
    return s;
}

__global__ __launch_bounds__(256) void csr_bucket_hist(const int* __restrict__ ru,
                                                       const int* __restrict__ rm,
                                                       const int* __restrict__ tm,
                                                       const int* __restrict__ tt,
                                                       int* __restrict__ bcnt) {
    __shared__ int h[256];
    const int t = threadIdx.x;
    h[t] = 0;
    __syncthreads();
    const SegInfo s = seg_decode(blockIdx.x, ru, rm, tm, tt);
#pragma unroll 4
    for (int i = 0; i < S1_EPB / 256; ++i) {
        const int e = s.e0 + t + i * 256;
        if (e < s.eN) atomicAdd(&h[s.dstA[e] >> s.sh], 1);
    }
    __syncthreads();
    if (t < s.nb) {
        const int c = h[t];
        if (c) atomicAdd(&bcnt[s.sbb + t], c);
    }
}

__global__ __launch_bounds__(1024) void csr_bscan(const int* __restrict__ bcnt,
                                                  int* __restrict__ bbase,
                                                  int* __restrict__ bcur,
                                                  int* __restrict__ rowptr) {
    __shared__ int sh[1024];
    const int t = threadIdx.x;
    const int v = (t < NB) ? bcnt[t] : 0;
    sh[t] = v;
    __syncthreads();
    for (int off = 1; off < 1024; off <<= 1) {
        const int add = (t >= off) ? sh[t - off] : 0;
        __syncthreads();
        sh[t] += add;
        __syncthreads();
    }
    const int ex = sh[t] - v;
    if (t < NB) { bbase[t] = ex; bcur[t] = ex; }
    if (t == NB - 1) bbase[NB] = ex + v;
    if (t == 0) rowptr[NTOT] = ETOT;
}

__global__ __launch_bounds__(256) void csr_bin(const int* __restrict__ ru,
                                               const int* __restrict__ rm,
                                               const int* __restrict__ tm,
                                               const int* __restrict__ tt,
                                               int* __restrict__ bcur,
                                               int* __restrict__ tmp) {
    __shared__ int h[256], st[256], gb[256], cu[256];
    __shared__ int rec[S1_EPB];
    __shared__ unsigned short bk[S1_EPB];
    const int t = threadIdx.x;
    h[t] = 0;
    __syncthreads();
    const SegInfo s = seg_decode(blockIdx.x, ru, rm, tm, tt);
    const int mask = (1 << s.sh) - 1;
#pragma unroll 4
    for (int i = 0; i < S1_EPB / 256; ++i) {
        const int e = s.e0 + t + i * 256;
        if (e < s.eN) atomicAdd(&h[s.dstA[e] >> s.sh], 1);
    }
    __syncthreads();
    const int v = h[t];
    cu[t] = v;
    __syncthreads();
    for (int off = 1; off < 256; off <<= 1) {
        const int add = (t >= off) ? cu[t - off] : 0;
        __syncthreads();
        cu[t] += add;
        __syncthreads();
    }
    st[t] = cu[t] - v;
    gb[t] = (t < s.nb && v) ? atomicAdd(&bcur[s.sbb + t], v) : 0;
    cu[t] = st[t];
    __syncthreads();
#pragma unroll 4
    for (int i = 0; i < S1_EPB / 256; ++i) {
        const int e = s.e0 + t + i * 256;
        if (e < s.eN) {
            const int d = s.dstA[e];
            const int lb = d >> s.sh;
            const int r = ((d & mask) << 18) | s.srcA[e];
            const int p = atomicAdd(&cu[lb], 1);
            rec[p] = r;
            bk[p] = (unsigned short)lb;
        }
    }
    __syncthreads();
    const int ecount = min(S1_EPB, s.eN - s.e0);
    for (int q = t; q < ecount; q += 256) {
        const int lb = bk[q];
        tmp[gb[lb] + (q - st[lb])] = rec[q];
    }
}

__global__ __launch_bounds__(256) void csr_sort(const int* __restrict__ tmp,
                                                const int* __restrict__ bbase,
                                                int* __restrict__ rowptr,
                                                int* __restrict__ sorted) {
    __shared__ int h[1024];
    __shared__ int part[256];
    __shared__ int outb[CAP];
    const int b = blockIdx.x;
    const int t = threadIdx.x;
    int c0, nctr;
    if (b < NB0)                 { c0 = OFF_RM + (b << 8);                nctr = min(256,  NMOV - (b << 8)); }
    else if (b < NB0 + NB1)      { const int j = b - NB0;                 c0 = OFF_RU + (j << 10); nctr = min(1024, NUSR - (j << 10)); }
    else if (b < NB0 + NB1 + NB2){ const int j = b - NB0 - NB1;           c0 = OFF_TM + (j << 9);  nctr = min(512,  NMOV - (j << 9)); }
    else                         { const int j = b - NB0 - NB1 - NB2;     c0 = OFF_TT + (j << 7);  nctr = min(128,  NTAG - (j << 7)); }
    for (int k = t; k < 1024; k += 256) h[k] = 0;
    __syncthreads();
    const int lo = bbase[b], hi = bbase[b + 1];
    const int n = hi - lo;
    for (int e = lo + t; e < hi; e += 256) atomicAdd(&h[tmp[e] >> 18], 1);
    __syncthreads();
    const int b4 = t * 4;
    const int a0 = h[b4], a1 = h[b4 + 1], a2 = h[b4 + 2], a3 = h[b4 + 3];
    const int sum = a0 + a1 + a2 + a3;
    part[t] = sum;
    __syncthreads();
    for (int off = 1; off < 256; off <<= 1) {
        const int add = (t >= off) ? part[t - off] : 0;
        __syncthreads();
        part[t] += add;
        __syncthreads();
    }
    int run = part[t] - sum;
    h[b4] = run; run += a0;
    h[b4 + 1] = run; run += a1;
    h[b4 + 2] = run; run += a2;
    h[b4 + 3] = run;
    __syncthreads();
    for (int k = t; k < nctr; k += 256) rowptr[c0 + k] = lo + h[k];
    __syncthreads();
    if (n <= CAP) {
        for (int e = lo + t; e < hi; e += 256) {
            const int r = tmp[e];
            const int p = atomicAdd(&h[r >> 18], 1);
            outb[p] = r & 0x3FFFF;
        }
        __syncthreads();
        for (int q = t; q < n; q += 256) sorted[lo + q] = outb[q];
    } else {
        for (int e = lo + t; e < hi; e += 256) {
            const int r = tmp[e];
            const int p = atomicAdd(&h[r >> 18], 1);
            sorted[lo + p] = r & 0x3FFFF;
        }
    }
}

// ---------------------------------------------------------------------------
// merged prep: f32->bf16 feature converts + weight pack + combined bias.
// block-range split: [0, GCVT) converts (float4 units); rest packs weights.
// ---------------------------------------------------------------------------
__global__ __launch_bounds__(256) void prep_all(
    const float* __restrict__ i0, unsigned short* __restrict__ o0, int n0,
    const float* __restrict__ i1, unsigned short* __restrict__ o1, int n1,
    const float* __restrict__ i2, unsigned short* __restrict__ o2, int n2,
    int gcvt,
    const float* __restrict__ movie_W, const float* __restrict__ Wn,
    const float* __restrict__ Ws, const float* __restrict__ bs,
    unsigned short* __restrict__ WB, float* __restrict__ bcc) {
    if ((int)blockIdx.x < gcvt) {
        int i = blockIdx.x * 256 + threadIdx.x;
        const float* in; unsigned short* out;
        if (i < n0) { in = i0; out = o0; }
        else if (i < n0 + n1) { in = i1; out = o1; i -= n0; }
        else if (i < n0 + n1 + n2) { in = i2; out = o2; i -= n0 + n1; }
        else return;
        const float4 v = ((const float4*)in)[i];
        ushort4 o;
        o.x = f2bf(v.x); o.y = f2bf(v.y); o.z = f2bf(v.z); o.w = f2bf(v.w);
        ((ushort4*)out)[i] = o;
        return;
    }
    const int i = (blockIdx.x - gcvt) * 256 + threadIdx.x;
    if (i < 256) {
        const int l = i >> 7, c = i & 127;
        bcc[i] = bs[(l * 4 + 0) * HDIM + c] + bs[(l * 4 + 3) * HDIM + c];
    }
    const int total = 8192 + 2 * 7 * WHH;
    if (i < total) {
        float v;
        if (i < 8192) {
            v = movie_W[i];
        } else {
            const int j = i - 8192;
            const int l = j / (7 * WHH);
            const int r = j % (7 * WHH);
            const int e = r / WHH;
            const int o = r % WHH;
            if (e < 4) v = Wn[(l * 4 + e) * WHH + o];
            else if (e == 4) v = Ws[(l * 4 + 1) * WHH + o];
            else if (e == 5) v = Ws[(l * 4 + 2) * WHH + o];
            else v = Ws[(l * 4 + 0) * WHH + o] + Ws[(l * 4 + 3) * WHH + o];
        }
        WB[i] = f2bf(v);
    }
}

// ---------------------------------------------------------------------------
// merged mean aggregation (round-5 design): 16-lane groups, bf16 in/out.
// ---------------------------------------------------------------------------
__global__ __launch_bounds__(256) void agg4(
    const unsigned short* __restrict__ f0, const int* __restrict__ rp0, unsigned short* __restrict__ o0,
    const unsigned short* __restrict__ f1, const int* __restrict__ rp1, unsigned short* __restrict__ o1,
    const unsigned short* __restrict__ f2, const int* __restrict__ rp2, unsigned short* __restrict__ o2,
    const unsigned short* __restrict__ f3, const int* __restrict__ rp3, unsigned short* __restrict__ o3,
    int c0, int c1, int c2, int c3,
    const int* __restrict__ sorted) {
    int g = blockIdx.x * 16 + (threadIdx.x >> 4);
    const unsigned short* feat; const int* rp; unsigned short* out;
    if (g < c0) { feat = f0; rp = rp0; out = o0; }
    else if (g < c1) { feat = f1; rp = rp1; out = o1; g -= c0; }
    else if (g < c2) { feat = f2; rp = rp2; out = o2; g -= c1; }
    else if (g < c3) { feat = f3; rp = rp3; out = o3; g -= c2; }
    else return;
    const int lane = threadIdx.x & 15;
    const int s = rp[g], e = rp[g + 1];
    float a[8];
#pragma unroll
    for (int k = 0; k < 8; ++k) a[k] = 0.f;
    int j = s;
    for (; j + 1 < e; j += 2) {
        const int s0 = sorted[j], s1 = sorted[j + 1];
        const bf16x8 v0 = *(const bf16x8*)&feat[(size_t)s0 * HDIM + lane * 8];
        const bf16x8 v1 = *(const bf16x8*)&feat[(size_t)s1 * HDIM + lane * 8];
#pragma unroll
        for (int k = 0; k < 8; ++k) a[k] += bf2f((unsigned short)v0[k]) + bf2f((unsigned short)v1[k]);
    }
    if (j < e) {
        const int s0 = sorted[j];
        const bf16x8 v0 = *(const bf16x8*)&feat[(size_t)s0 * HDIM + lane * 8];
#pragma unroll
        for (int k = 0; k < 8; ++k) a[k] += bf2f((unsigned short)v0[k]);
    }
    const float sc = (e > s) ? 1.0f / (float)(e - s) : 0.0f;
    bf16x8 o;
#pragma unroll
    for (int k = 0; k < 8; ++k) o[k] = (short)f2bf(a[k] * sc);
    *(bf16x8*)&out[(size_t)g * HDIM + lane * 8] = o;
}

// ---------------------------------------------------------------------------
// MFMA GEMM core: 2 row-tiles/wave, 128 rows/block, FULL-K register prefetch
// of X fragments (1 HBM round-trip per matrix per wave — round-6 fix).
// ---------------------------------------------------------------------------
template <int K>
__device__ __forceinline__ void gemm_core(
    const unsigned short* __restrict__ X1, const unsigned short* __restrict__ W1,
    const unsigned short* __restrict__ X2, const unsigned short* __restrict__ W2,
    const unsigned short* __restrict__ addv, const float* __restrict__ bias,
    void* __restrict__ out, int n, int out_f32, int leaky, int blk) {
    constexpr int NC = K / 32;
    const int lane = threadIdx.x & 63;
    const int w = threadIdx.x >> 6;
    const int fr = lane & 15;
    const int fq = lane >> 4;
    const int wrow0 = blk * 128 + w * 32;

    f32x4 acc[2][8];
#pragma unroll
    for (int t = 0; t < 2; ++t)
#pragma unroll
        for (int nn = 0; nn < 8; ++nn) acc[t][nn] = (f32x4){0.f, 0.f, 0.f, 0.f};

    const int nmat = X2 ? 2 : 1;
#pragma unroll 1
    for (int mat = 0; mat < nmat; ++mat) {
        const unsigned short* __restrict__ X = mat ? X2 : X1;
        const unsigned short* __restrict__ W = mat ? W2 : W1;
        int ra0 = wrow0 + fr;        if (ra0 >= n) ra0 = n - 1;
        int ra1 = wrow0 + 16 + fr;   if (ra1 >= n) ra1 = n - 1;
        const unsigned short* xp0 = X + (size_t)ra0 * K + fq * 8;
        const unsigned short* xp1 = X + (size_t)ra1 * K + fq * 8;
        // prefetch ALL X fragments for the full K (static -> stays in VGPRs)
        bf16x8 a0[NC], a1[NC];
#pragma unroll
        for (int c = 0; c < NC; ++c) {
            a0[c] = *(const bf16x8*)(xp0 + c * 32);
            a1[c] = *(const bf16x8*)(xp1 + c * 32);
        }
#pragma unroll
        for (int nn = 0; nn < 8; ++nn) {
            const unsigned short* wp = W + (size_t)(nn * 16 + fr) * K + fq * 8;
#pragma unroll
            for (int c = 0; c < NC; ++c) {
                const bf16x8 b = *(const bf16x8*)(wp + c * 32);
                acc[0][nn] = __builtin_amdgcn_mfma_f32_16x16x32_bf16(a0[c], b, acc[0][nn], 0, 0, 0);
                acc[1][nn] = __builtin_amdgcn_mfma_f32_16x16x32_bf16(a1[c], b, acc[1][nn], 0, 0, 0);
            }
        }
    }

    float bv[8];
#pragma unroll
    for (int nn = 0; nn < 8; ++nn) bv[nn] = bias ? bias[nn * 16 + fr] : 0.f;

#pragma unroll
    for (int t = 0; t < 2; ++t) {
#pragma unroll
        for (int j = 0; j < 4; ++j) {
            const int r = wrow0 + t * 16 + fq * 4 + j;
            if (r < n) {
#pragma unroll
                for (int nn = 0; nn < 8; ++nn) {
                    const int c = nn * 16 + fr;
                    float v = acc[t][nn][j] + bv[nn];
                    if (addv) v += bf2f(addv[(size_t)r * HDIM + c]);
                    if (leaky) v = v > 0.f ? v : 0.1f * v;
                    if (out_f32) ((float*)out)[(size_t)r * HDIM + c] = v;
                    else ((unsigned short*)out)[(size_t)r * HDIM + c] = f2bf(v);
                }
            }
        }
    }
}

// genre projection: single segment, K=64, f32 bias, bf16 out
__global__ __launch_bounds__(256) void gemm_genre(const unsigned short* __restrict__ X,
                                                  const unsigned short* __restrict__ W,
                                                  const float* __restrict__ bias,
                                                  unsigned short* __restrict__ out, int n) {
    gemm_core<FDIM>(X, W, nullptr, nullptr, nullptr, bias, out, n, 0, 0, blockIdx.x);
}

// two pre-transform GEMMs (movie + tag) in one launch
__global__ __launch_bounds__(256) void gemm_pre2(
    const unsigned short* __restrict__ Xa, const unsigned short* __restrict__ Wa,
    unsigned short* __restrict__ oa, int na, int nblka,
    const unsigned short* __restrict__ Xb, const unsigned short* __restrict__ Wb,
    unsigned short* __restrict__ ob, int nb) {
    const int b = blockIdx.x;
    if (b < nblka) gemm_core<HDIM>(Xa, Wa, nullptr, nullptr, nullptr, nullptr, oa, na, 0, 0, b);
    else           gemm_core<HDIM>(Xb, Wb, nullptr, nullptr, nullptr, nullptr, ob, nb, 0, 0, b - nblka);
}

// fat update kernel: up to 3 runtime segments (user / movie / tag)
struct USeg {
    const unsigned short* X1; const unsigned short* W1;
    const unsigned short* X2; const unsigned short* W2;
    const unsigned short* addv; const float* bias;
    void* out; int n; int nblk; int out_f32;
};

__global__ __launch_bounds__(256) void gemm_update(USeg s0, USeg s1, USeg s2) {
    int b = blockIdx.x;
    USeg s;
    if (b < s0.nblk) s = s0;
    else if (b < s0.nblk + s1.nblk) { s = s1; b -= s0.nblk; }
    else { s = s2; b -= s0.nblk + s1.nblk; }
    gemm_core<HDIM>(s.X1, s.W1, s.X2, s.W2, s.addv, s.bias, s.out, s.n, s.out_f32, 1, b);
}

// ---------------------------------------------------------------------------
extern "C" void kernel_launch(void* const* d_in, const int* in_sizes, int n_in,
                              void* d_out, int out_size, void* d_ws, size_t ws_size,
                              hipStream_t stream) {
    const float* genre    = (const float*)d_in[0];
    const float* user_emb = (const float*)d_in[1];
    const float* tag_emb  = (const float*)d_in[2];
    const float* movie_W  = (const float*)d_in[3];
    const float* movie_b  = (const float*)d_in[4];
    const float* Wn       = (const float*)d_in[5];
    const float* Wsf      = (const float*)d_in[6];
    const float* bsf      = (const float*)d_in[7];
    const int* rates_u    = (const int*)d_in[8];
    const int* rates_m    = (const int*)d_in[9];
    const int* tag_m      = (const int*)d_in[10];
    const int* tag_t      = (const int*)d_in[11];

    float* out_u = (float*)d_out;                 // NUSR x H (f32)
    float* out_m = out_u + (size_t)NUSR * HDIM;   // NMOV x H (f32)

    // ---- workspace carve-up ----
    char* w = (char*)d_ws;
    auto alloc = [&](size_t bytes) -> char* {
        char* p = w;
        w += (bytes + 511) & ~(size_t)511;
        return p;
    };
    unsigned short* ub  = (unsigned short*)alloc((size_t)NUSR * HDIM * 2);  // L0: bf16 user; L1: U2 scratch
    unsigned short* tb  = (unsigned short*)alloc((size_t)NTAG * HDIM * 2);
    unsigned short* gb  = (unsigned short*)alloc((size_t)NMOV * FDIM * 2);
    unsigned short* hm0 = (unsigned short*)alloc((size_t)NMOV * HDIM * 2);
    unsigned short* U1  = (unsigned short*)alloc((size_t)NUSR * HDIM * 2);
    unsigned short* M1  = (unsigned short*)alloc((size_t)NMOV * HDIM * 2);
    unsigned short* M2  = (unsigned short*)alloc((size_t)NMOV * HDIM * 2);
    unsigned short* M3  = (unsigned short*)alloc((size_t)NMOV * HDIM * 2);
    unsigned short* T1  = (unsigned short*)alloc((size_t)NTAG * HDIM * 2);
    unsigned short* T2  = (unsigned short*)alloc((size_t)NTAG * HDIM * 2);
    unsigned short* WB  = (unsigned short*)alloc((size_t)(8192 + 2 * 7 * WHH) * 2);
    float* bcc          = (float*)alloc(256 * 4);
    int* rowptr         = (int*)alloc((size_t)(NTOT + 1) * 4);
    int* sorted         = (int*)alloc((size_t)ETOT * 4);
    int* tmpb           = (int*)alloc((size_t)ETOT * 4);
    int* bcnt           = (int*)alloc((size_t)(NB + 1) * 4);
    int* bbase          = (int*)alloc((size_t)(NB + 1) * 4);
    int* bcur           = (int*)alloc((size_t)(NB + 1) * 4);

    const unsigned short* WB_mW = WB;
    const unsigned short* WL0 = WB + 8192;
    const unsigned short* WL1 = WB + 8192 + 7 * WHH;

    // ---- conversions + weight prep (one launch) ----
    const int n0 = NUSR * HDIM / 4, n1 = NTAG * HDIM / 4, n2 = NMOV * FDIM / 4;
    const int GCVT = cdiv(n0 + n1 + n2, 256);
    const int GWT  = cdiv(8192 + 2 * 7 * WHH, 256);
    prep_all<<<GCVT + GWT, 256, 0, stream>>>(user_emb, ub, n0, tag_emb, tb, n1, genre, gb, n2,
                                             GCVT, movie_W, Wn, Wsf, bsf, WB, bcc);

    // ---- bucketized CSR build ----
    hipMemsetAsync(bcnt, 0, (size_t)(NB + 1) * 4, stream);
    csr_bucket_hist<<<S1_NBLK, 256, 0, stream>>>(rates_u, rates_m, tag_m, tag_t, bcnt);
    csr_bscan<<<1, 1024, 0, stream>>>(bcnt, bbase, bcur, rowptr);
    csr_bin<<<S1_NBLK, 256, 0, stream>>>(rates_u, rates_m, tag_m, tag_t, bcur, tmpb);
    csr_sort<<<NB, 256, 0, stream>>>(tmpb, bbase, rowptr, sorted);

    const int GU = cdiv(NUSR, 128), GM = cdiv(NMOV, 128), GT = cdiv(NTAG, 128);

    // hm0 = genre @ movie_W.T + movie_b
    gemm_genre<<<GM, 256, 0, stream>>>(gb, WB_mW, movie_b, hm0, NMOV);

    // ================= layer 0 =================
    gemm_pre2<<<GM + GT, 256, 0, stream>>>(hm0, WL0 + 1 * WHH, M3, NMOV, GM,
                                           tb, WL0 + 3 * WHH, T1, NTAG);
    agg4<<<cdiv(NTOT, 16), 256, 0, stream>>>(
        M3, rowptr + OFF_RU, U1,
        ub, rowptr + OFF_RM, M1,
        T1, rowptr + OFF_TM, M2,
        hm0, rowptr + OFF_TT, T2,
        NUSR, NUSR + NMOV, NUSR + 2 * NMOV, NTOT, sorted);
    {
        USeg su = {ub, WL0 + 4 * WHH, nullptr, nullptr, U1, bsf + 1 * HDIM, U1, NUSR, GU, 0};
        USeg sm = {hm0, WL0 + 6 * WHH, M1, WL0 + 0 * WHH, M2, bcc, M2, NMOV, GM, 0};
        USeg st = {tb, WL0 + 5 * WHH, T2, WL0 + 2 * WHH, nullptr, bsf + 2 * HDIM, T2, NTAG, GT, 0};
        gemm_update<<<GU + GM + GT, 256, 0, stream>>>(su, sm, st);
    }

    // ================= layer 1 (tag update dead; outputs f32 -> d_out) =========
    gemm_pre2<<<GM + GT, 256, 0, stream>>>(M2, WL1 + 1 * WHH, M3, NMOV, GM,
                                           T2, WL1 + 3 * WHH, T1, NTAG);
    agg4<<<cdiv(NUSR + 2 * NMOV, 16), 256, 0, stream>>>(
        M3, rowptr + OFF_RU, ub,        // user agg -> U2 (= dead ub buffer)
        U1, rowptr + OFF_RM, M1,
        T1, rowptr + OFF_TM, hm0,
        nullptr, nullptr, nullptr,
        NUSR, NUSR + NMOV, NUSR + 2 * NMOV, NUSR + 2 * NMOV, sorted);
    {
        USeg su = {U1, WL1 + 4 * WHH, nullptr, nullptr, ub, bsf + 5 * HDIM, out_u, NUSR, GU, 1};
        USeg sm = {M2, WL1 + 6 * WHH, M1, WL1 + 0 * WHH, hm0, bcc + HDIM, out_m, NMOV, GM, 1};
        USeg sz = {nullptr, nullptr, nullptr, nullptr, nullptr, nullptr, nullptr, 0, 0, 0};
        gemm_update<<<GU + GM, 256, 0, stream>>>(su, sm, sz);
    }
}

// Round 7
// 561.175 us; speedup vs baseline: 1.0040x; 1.0040x over previous
//
#include <hip/hip_runtime.h>
#include <stdint.h>

// ---------------------------------------------------------------------------
// HeteroGraphSAGE encoder, MI355X round 7.
// Round-6 post-mortem: full-K prefetch at 2 row-tiles/wave pushed VGPR to 104
// — still in the 4-waves/SIMD band (cliff is at 64 VGPR), occupancy fell,
// 1.0 TB/s. Fix: per-wave tile 16 rows x 64 cols (acc 16 VGPR + K-prefetch
// 16 VGPR ~= 60 total), 512-thread blocks (8 waves: 4 row-groups x 2 col
// halves), __launch_bounds__(512,8) to pin VGPR<=64 -> 8 waves/SIMD with
// full-K X bytes in flight. CSR build / agg4 / prep unchanged.
// ---------------------------------------------------------------------------

#define NUSR 200000
#define NMOV 50000
#define NTAG 20000
#define FDIM 64
#define HDIM 128
#define NE1  800000
#define NE2  400000

#define OFF_RM 0
#define OFF_RU (NMOV)
#define OFF_TM (NMOV + NUSR)
#define OFF_TT (NMOV + NUSR + NMOV)
#define NTOT   (2 * NMOV + NUSR + NTAG)      // 320000
#define ETOT   (2 * NE1 + 2 * NE2)           // 2.4M
#define WHH    (HDIM * HDIM)

// bucket layout (round 4): mean ~4096 edges/bucket
#define NB0 196
#define NB1 196
#define NB2 98
#define NB3 157
#define NB  (NB0 + NB1 + NB2 + NB3)          // 647
#define S1_EPB 8192
#define S1_B0 98
#define S1_B1 98
#define S1_B2 49
#define S1_B3 49
#define S1_NBLK (S1_B0 + S1_B1 + S1_B2 + S1_B3)  // 294
#define CAP 6144

typedef short bf16x8 __attribute__((ext_vector_type(8)));
typedef float f32x4 __attribute__((ext_vector_type(4)));

static inline int cdiv(int a, int b) { return (a + b - 1) / b; }

__device__ __forceinline__ float bf2f(unsigned short u) {
    union { unsigned int i; float f; } c;
    c.i = ((unsigned int)u) << 16;
    return c.f;
}
__device__ __forceinline__ unsigned short f2bf(float f) {
    union { float f; unsigned int i; } c;
    c.f = f;
    unsigned int i = c.i;
    return (unsigned short)((i + 0x7fffu + ((i >> 16) & 1u)) >> 16);  // RNE
}

// ---------------------------------------------------------------------------
// CSR build (round-4 bucketized design, unchanged)
// ---------------------------------------------------------------------------
struct SegInfo {
    int e0, eN, sh, sbb, nb;
    const int* dstA;
    const int* srcA;
};
__device__ __forceinline__ SegInfo seg_decode(int blk, const int* ru, const int* rm,
                                              const int* tm, const int* tt) {
    SegInfo s;
    if (blk < S1_B0) {
        s.e0 = blk * S1_EPB; s.eN = NE1; s.sh = 8;  s.sbb = 0;                 s.nb = NB0;
        s.dstA = rm; s.srcA = ru;
    } else if (blk < S1_B0 + S1_B1) {
        s.e0 = (blk - S1_B0) * S1_EPB; s.eN = NE1; s.sh = 10; s.sbb = NB0;     s.nb = NB1;
        s.dstA = ru; s.srcA = rm;
    } else if (blk < S1_B0 + S1_B1 + S1_B2) {
        s.e0 = (blk - S1_B0 - S1_B1) * S1_EPB; s.eN = NE2; s.sh = 9;
        s.sbb = NB0 + NB1; s.nb = NB2;
        s.dstA = tm; s.srcA = tt;
    } else {
        s.e0 = (blk - S1_B0 - S1_B1 - S1_B2) * S1_EPB; s.eN = NE2; s.sh = 7;
        s.sbb = NB0 + NB1 + NB2; s.nb = NB3;
        s.dstA = tt; s.srcA = tm;
    }
    return s;
}

__global__ __launch_bounds__(256) void csr_bucket_hist(const int* __restrict__ ru,
                                                       const int* __restrict__ rm,
                                                       const int* __restrict__ tm,
                                                       const int* __restrict__ tt,
                                                       int* __restrict__ bcnt) {
    __shared__ int h[256];
    const int t = threadIdx.x;
    h[t] = 0;
    __syncthreads();
    const SegInfo s = seg_decode(blockIdx.x, ru, rm, tm, tt);
#pragma unroll 4
    for (int i = 0; i < S1_EPB / 256; ++i) {
        const int e = s.e0 + t + i * 256;
        if (e < s.eN) atomicAdd(&h[s.dstA[e] >> s.sh], 1);
    }
    __syncthreads();
    if (t < s.nb) {
        const int c = h[t];
        if (c) atomicAdd(&bcnt[s.sbb + t], c);
    }
}

__global__ __launch_bounds__(1024) void csr_bscan(const int* __restrict__ bcnt,
                                                  int* __restrict__ bbase,
                                                  int* __restrict__ bcur,
                                                  int* __restrict__ rowptr) {
    __shared__ int sh[1024];
    const int t = threadIdx.x;
    const int v = (t < NB) ? bcnt[t] : 0;
    sh[t] = v;
    __syncthreads();
    for (int off = 1; off < 1024; off <<= 1) {
        const int add = (t >= off) ? sh[t - off] : 0;
        __syncthreads();
        sh[t] += add;
        __syncthreads();
    }
    const int ex = sh[t] - v;
    if (t < NB) { bbase[t] = ex; bcur[t] = ex; }
    if (t == NB - 1) bbase[NB] = ex + v;
    if (t == 0) rowptr[NTOT] = ETOT;
}

__global__ __launch_bounds__(256) void csr_bin(const int* __restrict__ ru,
                                               const int* __restrict__ rm,
                                               const int* __restrict__ tm,
                                               const int* __restrict__ tt,
                                               int* __restrict__ bcur,
                                               int* __restrict__ tmp) {
    __shared__ int h[256], st[256], gb[256], cu[256];
    __shared__ int rec[S1_EPB];
    __shared__ unsigned short bk[S1_EPB];
    const int t = threadIdx.x;
    h[t] = 0;
    __syncthreads();
    const SegInfo s = seg_decode(blockIdx.x, ru, rm, tm, tt);
    const int mask = (1 << s.sh) - 1;
#pragma unroll 4
    for (int i = 0; i < S1_EPB / 256; ++i) {
        const int e = s.e0 + t + i * 256;
        if (e < s.eN) atomicAdd(&h[s.dstA[e] >> s.sh], 1);
    }
    __syncthreads();
    const int v = h[t];
    cu[t] = v;
    __syncthreads();
    for (int off = 1; off < 256; off <<= 1) {
        const int add = (t >= off) ? cu[t - off] : 0;
        __syncthreads();
        cu[t] += add;
        __syncthreads();
    }
    st[t] = cu[t] - v;
    gb[t] = (t < s.nb && v) ? atomicAdd(&bcur[s.sbb + t], v) : 0;
    cu[t] = st[t];
    __syncthreads();
#pragma unroll 4
    for (int i = 0; i < S1_EPB / 256; ++i) {
        const int e = s.e0 + t + i * 256;
        if (e < s.eN) {
            const int d = s.dstA[e];
            const int lb = d >> s.sh;
            const int r = ((d & mask) << 18) | s.srcA[e];
            const int p = atomicAdd(&cu[lb], 1);
            rec[p] = r;
            bk[p] = (unsigned short)lb;
        }
    }
    __syncthreads();
    const int ecount = min(S1_EPB, s.eN - s.e0);
    for (int q = t; q < ecount; q += 256) {
        const int lb = bk[q];
        tmp[gb[lb] + (q - st[lb])] = rec[q];
    }
}

__global__ __launch_bounds__(256) void csr_sort(const int* __restrict__ tmp,
                                                const int* __restrict__ bbase,
                                                int* __restrict__ rowptr,
                                                int* __restrict__ sorted) {
    __shared__ int h[1024];
    __shared__ int part[256];
    __shared__ int outb[CAP];
    const int b = blockIdx.x;
    const int t = threadIdx.x;
    int c0, nctr;
    if (b < NB0)                 { c0 = OFF_RM + (b << 8);                nctr = min(256,  NMOV - (b << 8)); }
    else if (b < NB0 + NB1)      { const int j = b - NB0;                 c0 = OFF_RU + (j << 10); nctr = min(1024, NUSR - (j << 10)); }
    else if (b < NB0 + NB1 + NB2){ const int j = b - NB0 - NB1;           c0 = OFF_TM + (j << 9);  nctr = min(512,  NMOV - (j << 9)); }
    else                         { const int j = b - NB0 - NB1 - NB2;     c0 = OFF_TT + (j << 7);  nctr = min(128,  NTAG - (j << 7)); }
    for (int k = t; k < 1024; k += 256) h[k] = 0;
    __syncthreads();
    const int lo = bbase[b], hi = bbase[b + 1];
    const int n = hi - lo;
    for (int e = lo + t; e < hi; e += 256) atomicAdd(&h[tmp[e] >> 18], 1);
    __syncthreads();
    const int b4 = t * 4;
    const int a0 = h[b4], a1 = h[b4 + 1], a2 = h[b4 + 2], a3 = h[b4 + 3];
    const int sum = a0 + a1 + a2 + a3;
    part[t] = sum;
    __syncthreads();
    for (int off = 1; off < 256; off <<= 1) {
        const int add = (t >= off) ? part[t - off] : 0;
        __syncthreads();
        part[t] += add;
        __syncthreads();
    }
    int run = part[t] - sum;
    h[b4] = run; run += a0;
    h[b4 + 1] = run; run += a1;
    h[b4 + 2] = run; run += a2;
    h[b4 + 3] = run;
    __syncthreads();
    for (int k = t; k < nctr; k += 256) rowptr[c0 + k] = lo + h[k];
    __syncthreads();
    if (n <= CAP) {
        for (int e = lo + t; e < hi; e += 256) {
            const int r = tmp[e];
            const int p = atomicAdd(&h[r >> 18], 1);
            outb[p] = r & 0x3FFFF;
        }
        __syncthreads();
        for (int q = t; q < n; q += 256) sorted[lo + q] = outb[q];
    } else {
        for (int e = lo + t; e < hi; e += 256) {
            const int r = tmp[e];
            const int p = atomicAdd(&h[r >> 18], 1);
            sorted[lo + p] = r & 0x3FFFF;
        }
    }
}

// ---------------------------------------------------------------------------
// merged prep: f32->bf16 feature converts + weight pack + combined bias.
// ---------------------------------------------------------------------------
__global__ __launch_bounds__(256) void prep_all(
    const float* __restrict__ i0, unsigned short* __restrict__ o0, int n0,
    const float* __restrict__ i1, unsigned short* __restrict__ o1, int n1,
    const float* __restrict__ i2, unsigned short* __restrict__ o2, int n2,
    int gcvt,
    const float* __restrict__ movie_W, const float* __restrict__ Wn,
    const float* __restrict__ Ws, const float* __restrict__ bs,
    unsigned short* __restrict__ WB, float* __restrict__ bcc) {
    if ((int)blockIdx.x < gcvt) {
        int i = blockIdx.x * 256 + threadIdx.x;
        const float* in; unsigned short* out;
        if (i < n0) { in = i0; out = o0; }
        else if (i < n0 + n1) { in = i1; out = o1; i -= n0; }
        else if (i < n0 + n1 + n2) { in = i2; out = o2; i -= n0 + n1; }
        else return;
        const float4 v = ((const float4*)in)[i];
        ushort4 o;
        o.x = f2bf(v.x); o.y = f2bf(v.y); o.z = f2bf(v.z); o.w = f2bf(v.w);
        ((ushort4*)out)[i] = o;
        return;
    }
    const int i = (blockIdx.x - gcvt) * 256 + threadIdx.x;
    if (i < 256) {
        const int l = i >> 7, c = i & 127;
        bcc[i] = bs[(l * 4 + 0) * HDIM + c] + bs[(l * 4 + 3) * HDIM + c];
    }
    const int total = 8192 + 2 * 7 * WHH;
    if (i < total) {
        float v;
        if (i < 8192) {
            v = movie_W[i];
        } else {
            const int j = i - 8192;
            const int l = j / (7 * WHH);
            const int r = j % (7 * WHH);
            const int e = r / WHH;
            const int o = r % WHH;
            if (e < 4) v = Wn[(l * 4 + e) * WHH + o];
            else if (e == 4) v = Ws[(l * 4 + 1) * WHH + o];
            else if (e == 5) v = Ws[(l * 4 + 2) * WHH + o];
            else v = Ws[(l * 4 + 0) * WHH + o] + Ws[(l * 4 + 3) * WHH + o];
        }
        WB[i] = f2bf(v);
    }
}

// ---------------------------------------------------------------------------
// merged mean aggregation (round-5 design): 16-lane groups, bf16 in/out.
// ---------------------------------------------------------------------------
__global__ __launch_bounds__(256) void agg4(
    const unsigned short* __restrict__ f0, const int* __restrict__ rp0, unsigned short* __restrict__ o0,
    const unsigned short* __restrict__ f1, const int* __restrict__ rp1, unsigned short* __restrict__ o1,
    const unsigned short* __restrict__ f2, const int* __restrict__ rp2, unsigned short* __restrict__ o2,
    const unsigned short* __restrict__ f3, const int* __restrict__ rp3, unsigned short* __restrict__ o3,
    int c0, int c1, int c2, int c3,
    const int* __restrict__ sorted) {
    int g = blockIdx.x * 16 + (threadIdx.x >> 4);
    const unsigned short* feat; const int* rp; unsigned short* out;
    if (g < c0) { feat = f0; rp = rp0; out = o0; }
    else if (g < c1) { feat = f1; rp = rp1; out = o1; g -= c0; }
    else if (g < c2) { feat = f2; rp = rp2; out = o2; g -= c1; }
    else if (g < c3) { feat = f3; rp = rp3; out = o3; g -= c2; }
    else return;
    const int lane = threadIdx.x & 15;
    const int s = rp[g], e = rp[g + 1];
    float a[8];
#pragma unroll
    for (int k = 0; k < 8; ++k) a[k] = 0.f;
    int j = s;
    for (; j + 1 < e; j += 2) {
        const int s0 = sorted[j], s1 = sorted[j + 1];
        const bf16x8 v0 = *(const bf16x8*)&feat[(size_t)s0 * HDIM + lane * 8];
        const bf16x8 v1 = *(const bf16x8*)&feat[(size_t)s1 * HDIM + lane * 8];
#pragma unroll
        for (int k = 0; k < 8; ++k) a[k] += bf2f((unsigned short)v0[k]) + bf2f((unsigned short)v1[k]);
    }
    if (j < e) {
        const int s0 = sorted[j];
        const bf16x8 v0 = *(const bf16x8*)&feat[(size_t)s0 * HDIM + lane * 8];
#pragma unroll
        for (int k = 0; k < 8; ++k) a[k] += bf2f((unsigned short)v0[k]);
    }
    const float sc = (e > s) ? 1.0f / (float)(e - s) : 0.0f;
    bf16x8 o;
#pragma unroll
    for (int k = 0; k < 8; ++k) o[k] = (short)f2bf(a[k] * sc);
    *(bf16x8*)&out[(size_t)g * HDIM + lane * 8] = o;
}

// ---------------------------------------------------------------------------
// MFMA GEMM core, round-7 shape: 512-thread blocks = 8 waves arranged as
// 4 row-groups x 2 col-halves. Per wave: 16 rows x 64 cols, acc 16 VGPR,
// full-K X prefetch 16 VGPR -> target <=64 VGPR => 8 waves/SIMD.
// ---------------------------------------------------------------------------
template <int K>
__device__ __forceinline__ void gemm_core(
    const unsigned short* __restrict__ X1, const unsigned short* __restrict__ W1,
    const unsigned short* __restrict__ X2, const unsigned short* __restrict__ W2,
    const unsigned short* __restrict__ addv, const float* __restrict__ bias,
    void* __restrict__ out, int n, int out_f32, int leaky, int blk) {
    constexpr int NC = K / 32;
    const int lane = threadIdx.x & 63;
    const int wv = threadIdx.x >> 6;       // 0..7
    const int wy = wv >> 1;                // row group 0..3
    const int wx = wv & 1;                 // col half 0..1
    const int fr = lane & 15;
    const int fq = lane >> 4;
    const int row0 = blk * 64 + wy * 16;
    const int cbase = wx * 64;

    f32x4 acc[4];
#pragma unroll
    for (int nn = 0; nn < 4; ++nn) acc[nn] = (f32x4){0.f, 0.f, 0.f, 0.f};

    const int nmat = X2 ? 2 : 1;
#pragma unroll 1
    for (int mat = 0; mat < nmat; ++mat) {
        const unsigned short* __restrict__ X = mat ? X2 : X1;
        const unsigned short* __restrict__ W = mat ? W2 : W1;
        int ra = row0 + fr;
        if (ra >= n) ra = n - 1;
        const unsigned short* xp = X + (size_t)ra * K + fq * 8;
        // full-K X prefetch (16 VGPR): one HBM round-trip per matrix
        bf16x8 a[NC];
#pragma unroll
        for (int c = 0; c < NC; ++c) a[c] = *(const bf16x8*)(xp + c * 32);
#pragma unroll
        for (int nn = 0; nn < 4; ++nn) {
            const unsigned short* wp = W + (size_t)(cbase + nn * 16 + fr) * K + fq * 8;
#pragma unroll
            for (int c = 0; c < NC; ++c) {
                const bf16x8 b = *(const bf16x8*)(wp + c * 32);
                acc[nn] = __builtin_amdgcn_mfma_f32_16x16x32_bf16(a[c], b, acc[nn], 0, 0, 0);
            }
        }
    }

    float bv[4];
#pragma unroll
    for (int nn = 0; nn < 4; ++nn) bv[nn] = bias ? bias[cbase + nn * 16 + fr] : 0.f;

#pragma unroll
    for (int j = 0; j < 4; ++j) {
        const int r = row0 + fq * 4 + j;
        if (r < n) {
#pragma unroll
            for (int nn = 0; nn < 4; ++nn) {
                const int c = cbase + nn * 16 + fr;
                float v = acc[nn][j] + bv[nn];
                if (addv) v += bf2f(addv[(size_t)r * HDIM + c]);
                if (leaky) v = v > 0.f ? v : 0.1f * v;
                if (out_f32) ((float*)out)[(size_t)r * HDIM + c] = v;
                else ((unsigned short*)out)[(size_t)r * HDIM + c] = f2bf(v);
            }
        }
    }
}

// genre projection: single segment, K=64, f32 bias, bf16 out
__global__ __launch_bounds__(512, 8) void gemm_genre(const unsigned short* __restrict__ X,
                                                     const unsigned short* __restrict__ W,
                                                     const float* __restrict__ bias,
                                                     unsigned short* __restrict__ out, int n) {
    gemm_core<FDIM>(X, W, nullptr, nullptr, nullptr, bias, out, n, 0, 0, blockIdx.x);
}

// two pre-transform GEMMs (movie + tag) in one launch
__global__ __launch_bounds__(512, 8) void gemm_pre2(
    const unsigned short* __restrict__ Xa, const unsigned short* __restrict__ Wa,
    unsigned short* __restrict__ oa, int na, int nblka,
    const unsigned short* __restrict__ Xb, const unsigned short* __restrict__ Wb,
    unsigned short* __restrict__ ob, int nb) {
    const int b = blockIdx.x;
    if (b < nblka) gemm_core<HDIM>(Xa, Wa, nullptr, nullptr, nullptr, nullptr, oa, na, 0, 0, b);
    else           gemm_core<HDIM>(Xb, Wb, nullptr, nullptr, nullptr, nullptr, ob, nb, 0, 0, b - nblka);
}

// fat update kernel: up to 3 runtime segments (user / movie / tag)
struct USeg {
    const unsigned short* X1; const unsigned short* W1;
    const unsigned short* X2; const unsigned short* W2;
    const unsigned short* addv; const float* bias;
    void* out; int n; int nblk; int out_f32;
};

__global__ __launch_bounds__(512, 8) void gemm_update(USeg s0, USeg s1, USeg s2) {
    int b = blockIdx.x;
    USeg s;
    if (b < s0.nblk) s = s0;
    else if (b < s0.nblk + s1.nblk) { s = s1; b -= s0.nblk; }
    else { s = s2; b -= s0.nblk + s1.nblk; }
    gemm_core<HDIM>(s.X1, s.W1, s.X2, s.W2, s.addv, s.bias, s.out, s.n, s.out_f32, 1, b);
}

// ---------------------------------------------------------------------------
extern "C" void kernel_launch(void* const* d_in, const int* in_sizes, int n_in,
                              void* d_out, int out_size, void* d_ws, size_t ws_size,
                              hipStream_t stream) {
    const float* genre    = (const float*)d_in[0];
    const float* user_emb = (const float*)d_in[1];
    const float* tag_emb  = (const float*)d_in[2];
    const float* movie_W  = (const float*)d_in[3];
    const float* movie_b  = (const float*)d_in[4];
    const float* Wn       = (const float*)d_in[5];
    const float* Wsf      = (const float*)d_in[6];
    const float* bsf      = (const float*)d_in[7];
    const int* rates_u    = (const int*)d_in[8];
    const int* rates_m    = (const int*)d_in[9];
    const int* tag_m      = (const int*)d_in[10];
    const int* tag_t      = (const int*)d_in[11];

    float* out_u = (float*)d_out;                 // NUSR x H (f32)
    float* out_m = out_u + (size_t)NUSR * HDIM;   // NMOV x H (f32)

    // ---- workspace carve-up ----
    char* w = (char*)d_ws;
    auto alloc = [&](size_t bytes) -> char* {
        char* p = w;
        w += (bytes + 511) & ~(size_t)511;
        return p;
    };
    unsigned short* ub  = (unsigned short*)alloc((size_t)NUSR * HDIM * 2);  // L0: bf16 user; L1: U2 scratch
    unsigned short* tb  = (unsigned short*)alloc((size_t)NTAG * HDIM * 2);
    unsigned short* gb  = (unsigned short*)alloc((size_t)NMOV * FDIM * 2);
    unsigned short* hm0 = (unsigned short*)alloc((size_t)NMOV * HDIM * 2);
    unsigned short* U1  = (unsigned short*)alloc((size_t)NUSR * HDIM * 2);
    unsigned short* M1  = (unsigned short*)alloc((size_t)NMOV * HDIM * 2);
    unsigned short* M2  = (unsigned short*)alloc((size_t)NMOV * HDIM * 2);
    unsigned short* M3  = (unsigned short*)alloc((size_t)NMOV * HDIM * 2);
    unsigned short* T1  = (unsigned short*)alloc((size_t)NTAG * HDIM * 2);
    unsigned short* T2  = (unsigned short*)alloc((size_t)NTAG * HDIM * 2);
    unsigned short* WB  = (unsigned short*)alloc((size_t)(8192 + 2 * 7 * WHH) * 2);
    float* bcc          = (float*)alloc(256 * 4);
    int* rowptr         = (int*)alloc((size_t)(NTOT + 1) * 4);
    int* sorted         = (int*)alloc((size_t)ETOT * 4);
    int* tmpb           = (int*)alloc((size_t)ETOT * 4);
    int* bcnt           = (int*)alloc((size_t)(NB + 1) * 4);
    int* bbase          = (int*)alloc((size_t)(NB + 1) * 4);
    int* bcur           = (int*)alloc((size_t)(NB + 1) * 4);

    const unsigned short* WB_mW = WB;
    const unsigned short* WL0 = WB + 8192;
    const unsigned short* WL1 = WB + 8192 + 7 * WHH;

    // ---- conversions + weight prep (one launch) ----
    const int n0 = NUSR * HDIM / 4, n1 = NTAG * HDIM / 4, n2 = NMOV * FDIM / 4;
    const int GCVT = cdiv(n0 + n1 + n2, 256);
    const int GWT  = cdiv(8192 + 2 * 7 * WHH, 256);
    prep_all<<<GCVT + GWT, 256, 0, stream>>>(user_emb, ub, n0, tag_emb, tb, n1, genre, gb, n2,
                                             GCVT, movie_W, Wn, Wsf, bsf, WB, bcc);

    // ---- bucketized CSR build ----
    hipMemsetAsync(bcnt, 0, (size_t)(NB + 1) * 4, stream);
    csr_bucket_hist<<<S1_NBLK, 256, 0, stream>>>(rates_u, rates_m, tag_m, tag_t, bcnt);
    csr_bscan<<<1, 1024, 0, stream>>>(bcnt, bbase, bcur, rowptr);
    csr_bin<<<S1_NBLK, 256, 0, stream>>>(rates_u, rates_m, tag_m, tag_t, bcur, tmpb);
    csr_sort<<<NB, 256, 0, stream>>>(tmpb, bbase, rowptr, sorted);

    const int GU = cdiv(NUSR, 64), GM = cdiv(NMOV, 64), GT = cdiv(NTAG, 64);

    // hm0 = genre @ movie_W.T + movie_b
    gemm_genre<<<GM, 512, 0, stream>>>(gb, WB_mW, movie_b, hm0, NMOV);

    // ================= layer 0 =================
    gemm_pre2<<<GM + GT, 512, 0, stream>>>(hm0, WL0 + 1 * WHH, M3, NMOV, GM,
                                           tb, WL0 + 3 * WHH, T1, NTAG);
    agg4<<<cdiv(NTOT, 16), 256, 0, stream>>>(
        M3, rowptr + OFF_RU, U1,
        ub, rowptr + OFF_RM, M1,
        T1, rowptr + OFF_TM, M2,
        hm0, rowptr + OFF_TT, T2,
        NUSR, NUSR + NMOV, NUSR + 2 * NMOV, NTOT, sorted);
    {
        USeg su = {ub, WL0 + 4 * WHH, nullptr, nullptr, U1, bsf + 1 * HDIM, U1, NUSR, GU, 0};
        USeg sm = {hm0, WL0 + 6 * WHH, M1, WL0 + 0 * WHH, M2, bcc, M2, NMOV, GM, 0};
        USeg st = {tb, WL0 + 5 * WHH, T2, WL0 + 2 * WHH, nullptr, bsf + 2 * HDIM, T2, NTAG, GT, 0};
        gemm_update<<<GU + GM + GT, 512, 0, stream>>>(su, sm, st);
    }

    // ================= layer 1 (tag update dead; outputs f32 -> d_out) =========
    gemm_pre2<<<GM + GT, 512, 0, stream>>>(M2, WL1 + 1 * WHH, M3, NMOV, GM,
                                           T2, WL1 + 3 * WHH, T1, NTAG);
    agg4<<<cdiv(NUSR + 2 * NMOV, 16), 256, 0, stream>>>(
        M3, rowptr + OFF_RU, ub,        // user agg -> U2 (= dead ub buffer)
        U1, rowptr + OFF_RM, M1,
        T1, rowptr + OFF_TM, hm0,
        nullptr, nullptr, nullptr,
        NUSR, NUSR + NMOV, NUSR + 2 * NMOV, NUSR + 2 * NMOV, sorted);
    {
        USeg su = {U1, WL1 + 4 * WHH, nullptr, nullptr, ub, bsf + 5 * HDIM, out_u, NUSR, GU, 1};
        USeg sm = {M2, WL1 + 6 * WHH, M1, WL1 + 0 * WHH, hm0, bcc + HDIM, out_m, NMOV, GM, 1};
        USeg sz = {nullptr, nullptr, nullptr, nullptr, nullptr, nullptr, nullptr, 0, 0, 0};
        gemm_update<<<GU + GM, 512, 0, stream>>>(su, sm, sz);
    }
}

// Round 9
// 516.701 us; speedup vs baseline: 1.0905x; 1.0861x over previous
//
#include <hip/hip_runtime.h>
#include <stdint.h>

// ---------------------------------------------------------------------------
// HeteroGraphSAGE encoder, MI355X round 9.
// Round-8 post-mortem: movie output corrupt (0.31), user fine -> bug isolated
// to the tag update's in-place alias (X2 == out == T2) which became a real
// race once grid-stride loops let waves desync unboundedly (no barriers).
// Fix: ht1 now written to a dedicated T3 buffer; layer-1 reads T3.
// Everything else identical to round 8 (W-stationary waves, 8 per-XCD
// weight/bias replicas, swapped-operand MFMA vector epilogue).
// ---------------------------------------------------------------------------

#define NUSR 200000
#define NMOV 50000
#define NTAG 20000
#define FDIM 64
#define HDIM 128
#define NE1  800000
#define NE2  400000

#define OFF_RM 0
#define OFF_RU (NMOV)
#define OFF_TM (NMOV + NUSR)
#define OFF_TT (NMOV + NUSR + NMOV)
#define NTOT   (2 * NMOV + NUSR + NTAG)      // 320000
#define ETOT   (2 * NE1 + 2 * NE2)           // 2.4M
#define WHH    (HDIM * HDIM)

// replicated weight block: [0,8192) movie_W; per layer l: 8192 + l*7*WHH +
//   e*WHH with e: 0..3 Wn[l,e]; 4 Ws[l,1]; 5 Ws[l,2]; 6 Ws[l,0]+Ws[l,3].
#define WTOT (8192 + 2 * 7 * WHH)            // 237568 bf16 elems per replica
#define BREP 768                              // f32 bias elems per replica
// bias replica layout: [0)movie_b [128)b_l0_user [256)b_l0_tag
//                      [384)bcc_l0 [512)b_l1_user [640)bcc_l1

// bucket layout (round 4): mean ~4096 edges/bucket
#define NB0 196
#define NB1 196
#define NB2 98
#define NB3 157
#define NB  (NB0 + NB1 + NB2 + NB3)          // 647
#define S1_EPB 8192
#define S1_B0 98
#define S1_B1 98
#define S1_B2 49
#define S1_B3 49
#define S1_NBLK (S1_B0 + S1_B1 + S1_B2 + S1_B3)  // 294
#define CAP 6144

typedef short bf16x8 __attribute__((ext_vector_type(8)));
typedef float f32x4 __attribute__((ext_vector_type(4)));

static inline int cdiv(int a, int b) { return (a + b - 1) / b; }

__device__ __forceinline__ float bf2f(unsigned short u) {
    union { unsigned int i; float f; } c;
    c.i = ((unsigned int)u) << 16;
    return c.f;
}
__device__ __forceinline__ unsigned short f2bf(float f) {
    union { float f; unsigned int i; } c;
    c.f = f;
    unsigned int i = c.i;
    return (unsigned short)((i + 0x7fffu + ((i >> 16) & 1u)) >> 16);  // RNE
}

// ---------------------------------------------------------------------------
// CSR build (round-4 bucketized design, unchanged)
// ---------------------------------------------------------------------------
struct SegInfo {
    int e0, eN, sh, sbb, nb;
    const int* dstA;
    const int* srcA;
};
__device__ __forceinline__ SegInfo seg_decode(int blk, const int* ru, const int* rm,
                                              const int* tm, const int* tt) {
    SegInfo s;
    if (blk < S1_B0) {
        s.e0 = blk * S1_EPB; s.eN = NE1; s.sh = 8;  s.sbb = 0;                 s.nb = NB0;
        s.dstA = rm; s.srcA = ru;
    } else if (blk < S1_B0 + S1_B1) {
        s.e0 = (blk - S1_B0) * S1_EPB; s.eN = NE1; s.sh = 10; s.sbb = NB0;     s.nb = NB1;
        s.dstA = ru; s.srcA = rm;
    } else if (blk < S1_B0 + S1_B1 + S1_B2) {
        s.e0 = (blk - S1_B0 - S1_B1) * S1_EPB; s.eN = NE2; s.sh = 9;
        s.sbb = NB0 + NB1; s.nb = NB2;
        s.dstA = tm; s.srcA = tt;
    } else {
        s.e0 = (blk - S1_B0 - S1_B1 - S1_B2) * S1_EPB; s.eN = NE2; s.sh = 7;
        s.sbb = NB0 + NB1 + NB2; s.nb = NB3;
        s.dstA = tt; s.srcA = tm;
    }
    return s;
}

__global__ __launch_bounds__(256) void csr_bucket_hist(const int* __restrict__ ru,
                                                       const int* __restrict__ rm,
                                                       const int* __restrict__ tm,
                                                       const int* __restrict__ tt,
                                                       int* __restrict__ bcnt) {
    __shared__ int h[256];
    const int t = threadIdx.x;
    h[t] = 0;
    __syncthreads();
    const SegInfo s = seg_decode(blockIdx.x, ru, rm, tm, tt);
#pragma unroll 4
    for (int i = 0; i < S1_EPB / 256; ++i) {
        const int e = s.e0 + t + i * 256;
        if (e < s.eN) atomicAdd(&h[s.dstA[e] >> s.sh], 1);
    }
    __syncthreads();
    if (t < s.nb) {
        const int c = h[t];
        if (c) atomicAdd(&bcnt[s.sbb + t], c);
    }
}

__global__ __launch_bounds__(1024) void csr_bscan(const int* __restrict__ bcnt,
                                                  int* __restrict__ bbase,
                                                  int* __restrict__ bcur,
                                                  int* __restrict__ rowptr) {
    __shared__ int sh[1024];
    const int t = threadIdx.x;
    const int v = (t < NB) ? bcnt[t] : 0;
    sh[t] = v;
    __syncthreads();
    for (int off = 1; off < 1024; off <<= 1) {
        const int add = (t >= off) ? sh[t - off] : 0;
        __syncthreads();
        sh[t] += add;
        __syncthreads();
    }
    const int ex = sh[t] - v;
    if (t < NB) { bbase[t] = ex; bcur[t] = ex; }
    if (t == NB - 1) bbase[NB] = ex + v;
    if (t == 0) rowptr[NTOT] = ETOT;
}

__global__ __launch_bounds__(256) void csr_bin(const int* __restrict__ ru,
                                               const int* __restrict__ rm,
                                               const int* __restrict__ tm,
                                               const int* __restrict__ tt,
                                               int* __restrict__ bcur,
                                               int* __restrict__ tmp) {
    __shared__ int h[256], st[256], gb[256], cu[256];
    __shared__ int rec[S1_EPB];
    __shared__ unsigned short bk[S1_EPB];
    const int t = threadIdx.x;
    h[t] = 0;
    __syncthreads();
    const SegInfo s = seg_decode(blockIdx.x, ru, rm, tm, tt);
    const int mask = (1 << s.sh) - 1;
#pragma unroll 4
    for (int i = 0; i < S1_EPB / 256; ++i) {
        const int e = s.e0 + t + i * 256;
        if (e < s.eN) atomicAdd(&h[s.dstA[e] >> s.sh], 1);
    }
    __syncthreads();
    const int v = h[t];
    cu[t] = v;
    __syncthreads();
    for (int off = 1; off < 256; off <<= 1) {
        const int add = (t >= off) ? cu[t - off] : 0;
        __syncthreads();
        cu[t] += add;
        __syncthreads();
    }
    st[t] = cu[t] - v;
    gb[t] = (t < s.nb && v) ? atomicAdd(&bcur[s.sbb + t], v) : 0;
    cu[t] = st[t];
    __syncthreads();
#pragma unroll 4
    for (int i = 0; i < S1_EPB / 256; ++i) {
        const int e = s.e0 + t + i * 256;
        if (e < s.eN) {
            const int d = s.dstA[e];
            const int lb = d >> s.sh;
            const int r = ((d & mask) << 18) | s.srcA[e];
            const int p = atomicAdd(&cu[lb], 1);
            rec[p] = r;
            bk[p] = (unsigned short)lb;
        }
    }
    __syncthreads();
    const int ecount = min(S1_EPB, s.eN - s.e0);
    for (int q = t; q < ecount; q += 256) {
        const int lb = bk[q];
        tmp[gb[lb] + (q - st[lb])] = rec[q];
    }
}

__global__ __launch_bounds__(256) void csr_sort(const int* __restrict__ tmp,
                                                const int* __restrict__ bbase,
                                                int* __restrict__ rowptr,
                                                int* __restrict__ sorted) {
    __shared__ int h[1024];
    __shared__ int part[256];
    __shared__ int outb[CAP];
    const int b = blockIdx.x;
    const int t = threadIdx.x;
    int c0, nctr;
    if (b < NB0)                 { c0 = OFF_RM + (b << 8);                nctr = min(256,  NMOV - (b << 8)); }
    else if (b < NB0 + NB1)      { const int j = b - NB0;                 c0 = OFF_RU + (j << 10); nctr = min(1024, NUSR - (j << 10)); }
    else if (b < NB0 + NB1 + NB2){ const int j = b - NB0 - NB1;           c0 = OFF_TM + (j << 9);  nctr = min(512,  NMOV - (j << 9)); }
    else                         { const int j = b - NB0 - NB1 - NB2;     c0 = OFF_TT + (j << 7);  nctr = min(128,  NTAG - (j << 7)); }
    for (int k = t; k < 1024; k += 256) h[k] = 0;
    __syncthreads();
    const int lo = bbase[b], hi = bbase[b + 1];
    const int n = hi - lo;
    for (int e = lo + t; e < hi; e += 256) atomicAdd(&h[tmp[e] >> 18], 1);
    __syncthreads();
    const int b4 = t * 4;
    const int a0 = h[b4], a1 = h[b4 + 1], a2 = h[b4 + 2], a3 = h[b4 + 3];
    const int sum = a0 + a1 + a2 + a3;
    part[t] = sum;
    __syncthreads();
    for (int off = 1; off < 256; off <<= 1) {
        const int add = (t >= off) ? part[t - off] : 0;
        __syncthreads();
        part[t] += add;
        __syncthreads();
    }
    int run = part[t] - sum;
    h[b4] = run; run += a0;
    h[b4 + 1] = run; run += a1;
    h[b4 + 2] = run; run += a2;
    h[b4 + 3] = run;
    __syncthreads();
    for (int k = t; k < nctr; k += 256) rowptr[c0 + k] = lo + h[k];
    __syncthreads();
    if (n <= CAP) {
        for (int e = lo + t; e < hi; e += 256) {
            const int r = tmp[e];
            const int p = atomicAdd(&h[r >> 18], 1);
            outb[p] = r & 0x3FFFF;
        }
        __syncthreads();
        for (int q = t; q < n; q += 256) sorted[lo + q] = outb[q];
    } else {
        for (int e = lo + t; e < hi; e += 256) {
            const int r = tmp[e];
            const int p = atomicAdd(&h[r >> 18], 1);
            sorted[lo + p] = r & 0x3FFFF;
        }
    }
}

// ---------------------------------------------------------------------------
// merged prep: f32->bf16 converts + 8-replica weight pack + 8-replica biases.
// ---------------------------------------------------------------------------
__global__ __launch_bounds__(256) void prep_all(
    const float* __restrict__ i0, unsigned short* __restrict__ o0, int n0,
    const float* __restrict__ i1, unsigned short* __restrict__ o1, int n1,
    const float* __restrict__ i2, unsigned short* __restrict__ o2, int n2,
    int gcvt,
    const float* __restrict__ movie_W, const float* __restrict__ movie_b,
    const float* __restrict__ Wn, const float* __restrict__ Ws,
    const float* __restrict__ bs,
    unsigned short* __restrict__ WB, float* __restrict__ BB) {
    if ((int)blockIdx.x < gcvt) {
        int i = blockIdx.x * 256 + threadIdx.x;
        const float* in; unsigned short* out;
        if (i < n0) { in = i0; out = o0; }
        else if (i < n0 + n1) { in = i1; out = o1; i -= n0; }
        else if (i < n0 + n1 + n2) { in = i2; out = o2; i -= n0 + n1; }
        else return;
        const float4 v = ((const float4*)in)[i];
        ushort4 o;
        o.x = f2bf(v.x); o.y = f2bf(v.y); o.z = f2bf(v.z); o.w = f2bf(v.w);
        ((ushort4*)out)[i] = o;
        return;
    }
    const int i = (blockIdx.x - gcvt) * 256 + threadIdx.x;
    if (i < BREP) {
        const int seg = i >> 7, c = i & 127;
        float bv;
        if (seg == 0)      bv = movie_b[c];
        else if (seg == 1) bv = bs[0 * 512 + 1 * 128 + c];
        else if (seg == 2) bv = bs[0 * 512 + 2 * 128 + c];
        else if (seg == 3) bv = bs[0 * 512 + 0 * 128 + c] + bs[0 * 512 + 3 * 128 + c];
        else if (seg == 4) bv = bs[1 * 512 + 1 * 128 + c];
        else               bv = bs[1 * 512 + 0 * 128 + c] + bs[1 * 512 + 3 * 128 + c];
#pragma unroll
        for (int r = 0; r < 8; ++r) BB[r * BREP + i] = bv;
    }
    if (i < WTOT) {
        float v;
        if (i < 8192) {
            v = movie_W[i];
        } else {
            const int j = i - 8192;
            const int l = j / (7 * WHH);
            const int r = j % (7 * WHH);
            const int e = r / WHH;
            const int o = r % WHH;
            if (e < 4) v = Wn[(l * 4 + e) * WHH + o];
            else if (e == 4) v = Ws[(l * 4 + 1) * WHH + o];
            else if (e == 5) v = Ws[(l * 4 + 2) * WHH + o];
            else v = Ws[(l * 4 + 0) * WHH + o] + Ws[(l * 4 + 3) * WHH + o];
        }
        const unsigned short bf = f2bf(v);
#pragma unroll
        for (int r = 0; r < 8; ++r) WB[(size_t)r * WTOT + i] = bf;
    }
}

// ---------------------------------------------------------------------------
// merged mean aggregation (round-5 design): 16-lane groups, bf16 in/out.
// ---------------------------------------------------------------------------
__global__ __launch_bounds__(256) void agg4(
    const unsigned short* __restrict__ f0, const int* __restrict__ rp0, unsigned short* __restrict__ o0,
    const unsigned short* __restrict__ f1, const int* __restrict__ rp1, unsigned short* __restrict__ o1,
    const unsigned short* __restrict__ f2, const int* __restrict__ rp2, unsigned short* __restrict__ o2,
    const unsigned short* __restrict__ f3, const int* __restrict__ rp3, unsigned short* __restrict__ o3,
    int c0, int c1, int c2, int c3,
    const int* __restrict__ sorted) {
    int g = blockIdx.x * 16 + (threadIdx.x >> 4);
    const unsigned short* feat; const int* rp; unsigned short* out;
    if (g < c0) { feat = f0; rp = rp0; out = o0; }
    else if (g < c1) { feat = f1; rp = rp1; out = o1; g -= c0; }
    else if (g < c2) { feat = f2; rp = rp2; out = o2; g -= c1; }
    else if (g < c3) { feat = f3; rp = rp3; out = o3; g -= c2; }
    else return;
    const int lane = threadIdx.x & 15;
    const int s = rp[g], e = rp[g + 1];
    float a[8];
#pragma unroll
    for (int k = 0; k < 8; ++k) a[k] = 0.f;
    int j = s;
    for (; j + 1 < e; j += 2) {
        const int s0 = sorted[j], s1 = sorted[j + 1];
        const bf16x8 v0 = *(const bf16x8*)&feat[(size_t)s0 * HDIM + lane * 8];
        const bf16x8 v1 = *(const bf16x8*)&feat[(size_t)s1 * HDIM + lane * 8];
#pragma unroll
        for (int k = 0; k < 8; ++k) a[k] += bf2f((unsigned short)v0[k]) + bf2f((unsigned short)v1[k]);
    }
    if (j < e) {
        const int s0 = sorted[j];
        const bf16x8 v0 = *(const bf16x8*)&feat[(size_t)s0 * HDIM + lane * 8];
#pragma unroll
        for (int k = 0; k < 8; ++k) a[k] += bf2f((unsigned short)v0[k]);
    }
    const float sc = (e > s) ? 1.0f / (float)(e - s) : 0.0f;
    bf16x8 o;
#pragma unroll
    for (int k = 0; k < 8; ++k) o[k] = (short)f2bf(a[k] * sc);
    *(bf16x8*)&out[(size_t)g * HDIM + lane * 8] = o;
}

// ---------------------------------------------------------------------------
// GEMM cores (round-8 design). Swapped-operand MFMA: D = mfma(Wfrag, Xfrag)
// -> lane owns one output ROW (row0+fr), cols cbase+nn*16+fq*4+{0..3}.
// Wave = 16 rows x 64 cols; block = 512 thr = 8 waves; grid-stride tiles.
// NOTE: no __syncthreads in the tile loop -> waves desync; X inputs must
// NEVER alias the output buffer (round-8 lesson: T2 in-place race).
// ---------------------------------------------------------------------------
template <bool HAS_ADD, bool HAS_BIAS, bool LEAKY, bool OUT_F32>
__device__ __forceinline__ void epilogue(const f32x4* acc, int r, int cbase, int fq,
                                         const unsigned short* __restrict__ addv,
                                         const float* __restrict__ bias,
                                         void* __restrict__ out, int n) {
    if (r >= n) return;
#pragma unroll
    for (int nn = 0; nn < 4; ++nn) {
        const int c0 = cbase + nn * 16 + fq * 4;
        float v0 = acc[nn][0], v1 = acc[nn][1], v2 = acc[nn][2], v3 = acc[nn][3];
        if (HAS_BIAS) {
            const float4 bv = *(const float4*)&bias[c0];
            v0 += bv.x; v1 += bv.y; v2 += bv.z; v3 += bv.w;
        }
        if (HAS_ADD) {
            const ushort4 ad = *(const ushort4*)&addv[(size_t)r * HDIM + c0];
            v0 += bf2f(ad.x); v1 += bf2f(ad.y); v2 += bf2f(ad.z); v3 += bf2f(ad.w);
        }
        if (LEAKY) {
            v0 = v0 > 0.f ? v0 : 0.1f * v0;
            v1 = v1 > 0.f ? v1 : 0.1f * v1;
            v2 = v2 > 0.f ? v2 : 0.1f * v2;
            v3 = v3 > 0.f ? v3 : 0.1f * v3;
        }
        if (OUT_F32) {
            float4 o; o.x = v0; o.y = v1; o.z = v2; o.w = v3;
            *(float4*)&((float*)out)[(size_t)r * HDIM + c0] = o;
        } else {
            ushort4 o;
            o.x = f2bf(v0); o.y = f2bf(v1); o.z = f2bf(v2); o.w = f2bf(v3);
            *(ushort4*)&((unsigned short*)out)[(size_t)r * HDIM + c0] = o;
        }
    }
}

// single-matrix, W-stationary (W frags live in VGPRs across the tile loop)
template <int K, bool HAS_ADD, bool HAS_BIAS, bool LEAKY, bool OUT_F32>
__device__ __forceinline__ void core_ws(
    const unsigned short* __restrict__ X, const unsigned short* __restrict__ W,
    const unsigned short* __restrict__ addv, const float* __restrict__ bias,
    void* __restrict__ out, int n, int bl, int nbseg) {
    constexpr int NC = K / 32;
    const int lane = threadIdx.x & 63;
    const int wv = threadIdx.x >> 6;
    const int wy = wv >> 1, wx = wv & 1;
    const int fr = lane & 15, fq = lane >> 4;
    const int cbase = wx * 64;

    bf16x8 wf[4][NC];
#pragma unroll
    for (int nn = 0; nn < 4; ++nn) {
        const unsigned short* wp = W + (size_t)(cbase + nn * 16 + fr) * K + fq * 8;
#pragma unroll
        for (int c = 0; c < NC; ++c) wf[nn][c] = *(const bf16x8*)(wp + c * 32);
    }

    const int ntiles = (n + 63) >> 6;
    for (int t = bl; t < ntiles; t += nbseg) {
        const int row0 = t * 64 + wy * 16;
        int ra = row0 + fr;
        if (ra >= n) ra = n - 1;
        const unsigned short* xp = X + (size_t)ra * K + fq * 8;
        bf16x8 xf[NC];
#pragma unroll
        for (int c = 0; c < NC; ++c) xf[c] = *(const bf16x8*)(xp + c * 32);
        f32x4 acc[4];
#pragma unroll
        for (int nn = 0; nn < 4; ++nn) acc[nn] = (f32x4){0.f, 0.f, 0.f, 0.f};
#pragma unroll
        for (int nn = 0; nn < 4; ++nn)
#pragma unroll
            for (int c = 0; c < NC; ++c)
                acc[nn] = __builtin_amdgcn_mfma_f32_16x16x32_bf16(wf[nn][c], xf[c], acc[nn], 0, 0, 0);
        epilogue<HAS_ADD, HAS_BIAS, LEAKY, OUT_F32>(acc, row0 + fr, cbase, fq, addv, bias, out, n);
    }
}

// two-matrix (movie/tag updates): W reloaded per tile (from XCD-local replica)
template <bool HAS_ADD, bool HAS_BIAS, bool LEAKY, bool OUT_F32>
__device__ __forceinline__ void core_2m(
    const unsigned short* __restrict__ X1, const unsigned short* __restrict__ W1,
    const unsigned short* __restrict__ X2, const unsigned short* __restrict__ W2,
    const unsigned short* __restrict__ addv, const float* __restrict__ bias,
    void* __restrict__ out, int n, int bl, int nbseg) {
    constexpr int NC = 4;
    const int lane = threadIdx.x & 63;
    const int wv = threadIdx.x >> 6;
    const int wy = wv >> 1, wx = wv & 1;
    const int fr = lane & 15, fq = lane >> 4;
    const int cbase = wx * 64;

    const int ntiles = (n + 63) >> 6;
    for (int t = bl; t < ntiles; t += nbseg) {
        const int row0 = t * 64 + wy * 16;
        int ra = row0 + fr;
        if (ra >= n) ra = n - 1;
        f32x4 acc[4];
#pragma unroll
        for (int nn = 0; nn < 4; ++nn) acc[nn] = (f32x4){0.f, 0.f, 0.f, 0.f};
#pragma unroll 1
        for (int mat = 0; mat < 2; ++mat) {
            const unsigned short* __restrict__ X = mat ? X2 : X1;
            const unsigned short* __restrict__ W = mat ? W2 : W1;
            const unsigned short* xp = X + (size_t)ra * HDIM + fq * 8;
            bf16x8 xf[NC];
#pragma unroll
            for (int c = 0; c < NC; ++c) xf[c] = *(const bf16x8*)(xp + c * 32);
#pragma unroll
            for (int nn = 0; nn < 4; ++nn) {
                const unsigned short* wp = W + (size_t)(cbase + nn * 16 + fr) * HDIM + fq * 8;
#pragma unroll
                for (int c = 0; c < NC; ++c) {
                    const bf16x8 b = *(const bf16x8*)(wp + c * 32);
                    acc[nn] = __builtin_amdgcn_mfma_f32_16x16x32_bf16(b, xf[c], acc[nn], 0, 0, 0);
                }
            }
        }
        epilogue<HAS_ADD, HAS_BIAS, LEAKY, OUT_F32>(acc, row0 + fr, cbase, fq, addv, bias, out, n);
    }
}

// genre projection: K=64, bias, bf16 out
__global__ __launch_bounds__(512, 4) void gemm_genre(const unsigned short* __restrict__ X,
                                                     const unsigned short* __restrict__ WB,
                                                     const float* __restrict__ BB,
                                                     unsigned short* __restrict__ out, int n) {
    const int rep = blockIdx.x & 7;
    core_ws<FDIM, false, true, false, false>(X, WB + (size_t)rep * WTOT,
                                             nullptr, BB + rep * BREP, out, n,
                                             blockIdx.x, gridDim.x);
}

// two pre-transform GEMMs (movie + tag), both W-stationary
__global__ __launch_bounds__(512, 4) void gemm_pre2(
    const unsigned short* __restrict__ Xa, unsigned short* __restrict__ oa, int na, int nba,
    const unsigned short* __restrict__ Xb, unsigned short* __restrict__ ob, int nb_,
    const unsigned short* __restrict__ WB, int offA, int offB) {
    const int b = blockIdx.x;
    const int rep = b & 7;
    const unsigned short* WR = WB + (size_t)rep * WTOT;
    if (b < nba)
        core_ws<HDIM, false, false, false, false>(Xa, WR + offA, nullptr, nullptr, oa, na, b, nba);
    else
        core_ws<HDIM, false, false, false, false>(Xb, WR + offB, nullptr, nullptr, ob, nb_,
                                                  b - nba, (int)gridDim.x - nba);
}

// layer-0 update: user(ws) + movie(2m) + tag(2m -> T3, NOT in-place)
__global__ __launch_bounds__(512, 4) void upd_l0(
    const unsigned short* __restrict__ ub, const unsigned short* __restrict__ U1v,
    unsigned short* __restrict__ U1o,
    const unsigned short* __restrict__ hm0, const unsigned short* __restrict__ M1,
    const unsigned short* __restrict__ M2v, unsigned short* __restrict__ M2o,
    const unsigned short* __restrict__ tb, const unsigned short* __restrict__ T2v,
    unsigned short* __restrict__ T3o,
    const unsigned short* __restrict__ WB, const float* __restrict__ BB,
    int nbu, int nbm, int nbt) {
    const int b = blockIdx.x;
    const int rep = b & 7;
    const unsigned short* WL0 = WB + (size_t)rep * WTOT + 8192;
    const float* BR = BB + rep * BREP;
    if (b < nbu) {
        core_ws<HDIM, true, true, true, false>(ub, WL0 + 4 * WHH, U1v, BR + 128, U1o, NUSR, b, nbu);
    } else if (b < nbu + nbm) {
        core_2m<true, true, true, false>(hm0, WL0 + 6 * WHH, M1, WL0 + 0 * WHH, M2v, BR + 384,
                                         M2o, NMOV, b - nbu, nbm);
    } else {
        core_2m<false, true, true, false>(tb, WL0 + 5 * WHH, T2v, WL0 + 2 * WHH, nullptr, BR + 256,
                                          T3o, NTAG, b - nbu - nbm, nbt);
    }
}

// layer-1 update: user(ws, f32 out) + movie(2m, f32 out); tag dead
__global__ __launch_bounds__(512, 4) void upd_l1(
    const unsigned short* __restrict__ U1, const unsigned short* __restrict__ U2v,
    float* __restrict__ out_u,
    const unsigned short* __restrict__ M2, const unsigned short* __restrict__ M1,
    const unsigned short* __restrict__ M3v, float* __restrict__ out_m,
    const unsigned short* __restrict__ WB, const float* __restrict__ BB,
    int nbu, int nbm) {
    const int b = blockIdx.x;
    const int rep = b & 7;
    const unsigned short* WL1 = WB + (size_t)rep * WTOT + 8192 + 7 * WHH;
    const float* BR = BB + rep * BREP;
    if (b < nbu) {
        core_ws<HDIM, true, true, true, true>(U1, WL1 + 4 * WHH, U2v, BR + 512, out_u, NUSR, b, nbu);
    } else {
        core_2m<true, true, true, true>(M2, WL1 + 6 * WHH, M1, WL1 + 0 * WHH, M3v, BR + 640,
                                        out_m, NMOV, b - nbu, nbm);
    }
}

// ---------------------------------------------------------------------------
extern "C" void kernel_launch(void* const* d_in, const int* in_sizes, int n_in,
                              void* d_out, int out_size, void* d_ws, size_t ws_size,
                              hipStream_t stream) {
    const float* genre    = (const float*)d_in[0];
    const float* user_emb = (const float*)d_in[1];
    const float* tag_emb  = (const float*)d_in[2];
    const float* movie_W  = (const float*)d_in[3];
    const float* movie_b  = (const float*)d_in[4];
    const float* Wn       = (const float*)d_in[5];
    const float* Wsf      = (const float*)d_in[6];
    const float* bsf      = (const float*)d_in[7];
    const int* rates_u    = (const int*)d_in[8];
    const int* rates_m    = (const int*)d_in[9];
    const int* tag_m      = (const int*)d_in[10];
    const int* tag_t      = (const int*)d_in[11];

    float* out_u = (float*)d_out;                 // NUSR x H (f32)
    float* out_m = out_u + (size_t)NUSR * HDIM;   // NMOV x H (f32)

    // ---- workspace carve-up ----
    char* w = (char*)d_ws;
    auto alloc = [&](size_t bytes) -> char* {
        char* p = w;
        w += (bytes + 511) & ~(size_t)511;
        return p;
    };
    unsigned short* ub  = (unsigned short*)alloc((size_t)NUSR * HDIM * 2);  // L0: bf16 user; L1: U2 scratch
    unsigned short* tb  = (unsigned short*)alloc((size_t)NTAG * HDIM * 2);
    unsigned short* gb  = (unsigned short*)alloc((size_t)NMOV * FDIM * 2);
    unsigned short* hm0 = (unsigned short*)alloc((size_t)NMOV * HDIM * 2);
    unsigned short* U1  = (unsigned short*)alloc((size_t)NUSR * HDIM * 2);
    unsigned short* M1  = (unsigned short*)alloc((size_t)NMOV * HDIM * 2);
    unsigned short* M2  = (unsigned short*)alloc((size_t)NMOV * HDIM * 2);
    unsigned short* M3  = (unsigned short*)alloc((size_t)NMOV * HDIM * 2);
    unsigned short* T1  = (unsigned short*)alloc((size_t)NTAG * HDIM * 2);
    unsigned short* T2  = (unsigned short*)alloc((size_t)NTAG * HDIM * 2);
    unsigned short* T3  = (unsigned short*)alloc((size_t)NTAG * HDIM * 2);  // ht1 (race fix)
    unsigned short* WB  = (unsigned short*)alloc((size_t)8 * WTOT * 2);     // 8 replicas
    float* BB           = (float*)alloc((size_t)8 * BREP * 4);
    int* rowptr         = (int*)alloc((size_t)(NTOT + 1) * 4);
    int* sorted         = (int*)alloc((size_t)ETOT * 4);
    int* tmpb           = (int*)alloc((size_t)ETOT * 4);
    int* bcnt           = (int*)alloc((size_t)(NB + 1) * 4);
    int* bbase          = (int*)alloc((size_t)(NB + 1) * 4);
    int* bcur           = (int*)alloc((size_t)(NB + 1) * 4);

    // ---- conversions + replicated weight prep (one launch) ----
    const int n0 = NUSR * HDIM / 4, n1 = NTAG * HDIM / 4, n2 = NMOV * FDIM / 4;
    const int GCVT = cdiv(n0 + n1 + n2, 256);
    const int GWT  = cdiv(WTOT, 256);
    prep_all<<<GCVT + GWT, 256, 0, stream>>>(user_emb, ub, n0, tag_emb, tb, n1, genre, gb, n2,
                                             GCVT, movie_W, movie_b, Wn, Wsf, bsf, WB, BB);

    // ---- bucketized CSR build ----
    hipMemsetAsync(bcnt, 0, (size_t)(NB + 1) * 4, stream);
    csr_bucket_hist<<<S1_NBLK, 256, 0, stream>>>(rates_u, rates_m, tag_m, tag_t, bcnt);
    csr_bscan<<<1, 1024, 0, stream>>>(bcnt, bbase, bcur, rowptr);
    csr_bin<<<S1_NBLK, 256, 0, stream>>>(rates_u, rates_m, tag_m, tag_t, bcur, tmpb);
    csr_sort<<<NB, 256, 0, stream>>>(tmpb, bbase, rowptr, sorted);

    // tiles / grid-stride block counts (~4 tiles per block)
    const int TU = cdiv(NUSR, 64), TM = cdiv(NMOV, 64), TT = cdiv(NTAG, 64);
    const int NBU = cdiv(TU, 4), NBM = cdiv(TM, 4), NBT = cdiv(TT, 4);

    // hm0 = genre @ movie_W.T + movie_b
    gemm_genre<<<NBM, 512, 0, stream>>>(gb, WB, BB, hm0, NMOV);

    // ================= layer 0 =================
    gemm_pre2<<<NBM + NBT, 512, 0, stream>>>(hm0, M3, NMOV, NBM, tb, T1, NTAG,
                                             WB, 8192 + 1 * WHH, 8192 + 3 * WHH);
    agg4<<<cdiv(NTOT, 16), 256, 0, stream>>>(
        M3, rowptr + OFF_RU, U1,
        ub, rowptr + OFF_RM, M1,
        T1, rowptr + OFF_TM, M2,
        hm0, rowptr + OFF_TT, T2,
        NUSR, NUSR + NMOV, NUSR + 2 * NMOV, NTOT, sorted);
    upd_l0<<<NBU + NBM + NBT, 512, 0, stream>>>(ub, U1, U1, hm0, M1, M2, M2,
                                                tb, T2, T3, WB, BB, NBU, NBM, NBT);

    // ================= layer 1 (tag update dead; outputs f32 -> d_out) =========
    gemm_pre2<<<NBM + NBT, 512, 0, stream>>>(M2, M3, NMOV, NBM, T3, T1, NTAG,
                                             WB, 8192 + 7 * WHH + 1 * WHH, 8192 + 7 * WHH + 3 * WHH);
    agg4<<<cdiv(NUSR + 2 * NMOV, 16), 256, 0, stream>>>(
        M3, rowptr + OFF_RU, ub,        // user agg -> U2 (= dead ub buffer)
        U1, rowptr + OFF_RM, M1,
        T1, rowptr + OFF_TM, hm0,
        nullptr, nullptr, nullptr,
        NUSR, NUSR + NMOV, NUSR + 2 * NMOV, NUSR + 2 * NMOV, sorted);
    upd_l1<<<NBU + NBM, 512, 0, stream>>>(U1, ub, out_u, M2, M1, hm0, out_m,
                                          WB, BB, NBU, NBM);
}